// Round 3
// baseline (392.906 us; speedup 1.0000x reference)
//
#include <hip/hip_runtime.h>
#include <hip/hip_bf16.h>

#define B_DIM 2048
#define M_DIM 8192
#define D_DIM 2048
#define EPSN 1e-8f
#define ALPHA_C 0.5f
#define SIM_T 0.5f

typedef __attribute__((ext_vector_type(8))) short short8;
typedef __attribute__((ext_vector_type(4))) float f32x4;

__device__ inline void split_bf16(float x, ushort& h, ushort& l) {
    __hip_bfloat16 hi = __float2bfloat16(x);          // RNE
    float res = x - __bfloat162float(hi);
    __hip_bfloat16 lo = __float2bfloat16(res);
    h = *(ushort*)&hi; l = *(ushort*)&lo;
}

// ---------------- Kernel 1: normalize row, split fp32 -> bf16 hi/lo ----------------
// Row is pre-scaled by 1/max(||row||,eps) so the GEMM needs no epilogue scaling.
__global__ __launch_bounds__(256) void prep_kernel(const float* __restrict__ q,
                                                   const float* __restrict__ s,
                                                   ushort* __restrict__ Ah, ushort* __restrict__ Al,
                                                   ushort* __restrict__ Bh, ushort* __restrict__ Bl) {
    const int row = blockIdx.x;
    const int tid = threadIdx.x;
    const float* src;
    ushort *dh, *dl;
    if (row < B_DIM) {
        src = q + (size_t)row * D_DIM;
        dh = Ah + (size_t)row * D_DIM; dl = Al + (size_t)row * D_DIM;
    } else {
        int r = row - B_DIM;
        src = s + (size_t)r * D_DIM;
        dh = Bh + (size_t)r * D_DIM; dl = Bl + (size_t)r * D_DIM;
    }
    const float4* src4 = (const float4*)src;
    float4 v0 = src4[tid];
    float4 v1 = src4[tid + 256];
    float acc = v0.x * v0.x + v0.y * v0.y + v0.z * v0.z + v0.w * v0.w
              + v1.x * v1.x + v1.y * v1.y + v1.z * v1.z + v1.w * v1.w;
    #pragma unroll
    for (int o = 32; o > 0; o >>= 1) acc += __shfl_down(acc, o, 64);
    __shared__ float red[4];
    if ((tid & 63) == 0) red[tid >> 6] = acc;
    __syncthreads();
    const float tot = red[0] + red[1] + red[2] + red[3];
    const float scale = 1.0f / fmaxf(sqrtf(tot), EPSN);

    float xs0[4] = {v0.x * scale, v0.y * scale, v0.z * scale, v0.w * scale};
    float xs1[4] = {v1.x * scale, v1.y * scale, v1.z * scale, v1.w * scale};
    ushort4 h0, l0, h1, l1;
    ushort *hp0 = (ushort*)&h0, *lp0 = (ushort*)&l0, *hp1 = (ushort*)&h1, *lp1 = (ushort*)&l1;
    #pragma unroll
    for (int e = 0; e < 4; e++) { split_bf16(xs0[e], hp0[e], lp0[e]); split_bf16(xs1[e], hp1[e], lp1[e]); }
    ((ushort4*)dh)[tid] = h0;       ((ushort4*)dh)[tid + 256] = h1;
    ((ushort4*)dl)[tid] = l0;       ((ushort4*)dl)[tid + 256] = l1;
}

// ---------------- Kernel 2: split-bf16 MFMA NT GEMM with XOR-swizzled LDS ----------
// sims[b,m] = (Ah[b]+Al[b]) . (Bh[m]+Bl[m]), dropping lo.lo
// Swizzle: row r's 16B chunk c lives at chunk slot c ^ ((r>>1)&3) -> fragment reads
// spread 16 rows over all 8 bank-slots (2-way = free) instead of 8-way conflicts.
#define TK 32

#define GLOAD_LDS16(g, l) \
    __builtin_amdgcn_global_load_lds((const __attribute__((address_space(1))) void*)(g), \
                                     (__attribute__((address_space(3))) void*)(l), 16, 0, 0)

__global__ __launch_bounds__(256) void gemm_mfma(const ushort* __restrict__ Ah,
                                                 const ushort* __restrict__ Al,
                                                 const ushort* __restrict__ Bh,
                                                 const ushort* __restrict__ Bl,
                                                 float* __restrict__ C) {
    __shared__ ushort sAh[128][TK];
    __shared__ ushort sAl[128][TK];
    __shared__ ushort sBh[128][TK];
    __shared__ ushort sBl[128][TK];

    const int tid = threadIdx.x;
    const int wave = tid >> 6;
    const int lane = tid & 63;
    const int row0 = blockIdx.y * 128;
    const int col0 = blockIdx.x * 128;
    const int wm = (wave >> 1) * 64;
    const int wn = (wave & 1) * 64;

    f32x4 acc[4][4];
    #pragma unroll
    for (int i = 0; i < 4; i++)
        #pragma unroll
        for (int j = 0; j < 4; j++) acc[i][j] = (f32x4){0.f, 0.f, 0.f, 0.f};

    // staging: lane L fetches row L>>2, global chunk (L&3)^((L>>3)&3) of a 16-row
    // group; lands at LDS slot L&3 => stored slot = c ^ ((r>>1)&3). Same 1KB
    // region per wave-load -> coalescing unchanged.
    const int lrow = lane >> 2;
    const int lke  = (((lane & 3) ^ ((lane >> 3) & 3))) * 8;
    const size_t gA0 = (size_t)(row0 + wave * 32 + lrow) * D_DIM + lke;
    const size_t gA1 = gA0 + (size_t)16 * D_DIM;
    const size_t gB0 = (size_t)(col0 + wave * 32 + lrow) * D_DIM + lke;
    const size_t gB1 = gB0 + (size_t)16 * D_DIM;
    ushort* lA0  = &sAh[wave * 32][0];   ushort* lA1  = &sAh[wave * 32 + 16][0];
    ushort* lAl0 = &sAl[wave * 32][0];   ushort* lAl1 = &sAl[wave * 32 + 16][0];
    ushort* lB0  = &sBh[wave * 32][0];   ushort* lB1  = &sBh[wave * 32 + 16][0];
    ushort* lBl0 = &sBl[wave * 32][0];   ushort* lBl1 = &sBl[wave * 32 + 16][0];

    const int fr  = lane & 15;                                   // fragment row
    const int swz = (((lane >> 4) ^ ((fr >> 1) & 3))) * 8;       // swizzled k-chunk

    for (int k0 = 0; k0 < D_DIM; k0 += TK) {
        __syncthreads();
        GLOAD_LDS16(Ah + gA0 + k0, lA0);
        GLOAD_LDS16(Ah + gA1 + k0, lA1);
        GLOAD_LDS16(Al + gA0 + k0, lAl0);
        GLOAD_LDS16(Al + gA1 + k0, lAl1);
        GLOAD_LDS16(Bh + gB0 + k0, lB0);
        GLOAD_LDS16(Bh + gB1 + k0, lB1);
        GLOAD_LDS16(Bl + gB0 + k0, lBl0);
        GLOAD_LDS16(Bl + gB1 + k0, lBl1);
        __syncthreads();

        short8 avh[4], avl[4], bvh[4], bvl[4];
        #pragma unroll
        for (int i = 0; i < 4; i++) {
            avh[i] = *(const short8*)&sAh[wm + i * 16 + fr][swz];
            avl[i] = *(const short8*)&sAl[wm + i * 16 + fr][swz];
            bvh[i] = *(const short8*)&sBh[wn + i * 16 + fr][swz];
            bvl[i] = *(const short8*)&sBl[wn + i * 16 + fr][swz];
        }
        #pragma unroll
        for (int i = 0; i < 4; i++)
            #pragma unroll
            for (int j = 0; j < 4; j++) {
                acc[i][j] = __builtin_amdgcn_mfma_f32_16x16x32_bf16(avh[i], bvh[j], acc[i][j], 0, 0, 0);
                acc[i][j] = __builtin_amdgcn_mfma_f32_16x16x32_bf16(avh[i], bvl[j], acc[i][j], 0, 0, 0);
                acc[i][j] = __builtin_amdgcn_mfma_f32_16x16x32_bf16(avl[i], bvh[j], acc[i][j], 0, 0, 0);
            }
    }

    // epilogue: C/D layout col=lane&15, row=(lane>>4)*4+reg (no scaling needed)
    const int cn = lane & 15;
    const int cr = (lane >> 4) * 4;
    #pragma unroll
    for (int j = 0; j < 4; j++) {
        const int col = col0 + wn + j * 16 + cn;
        #pragma unroll
        for (int i = 0; i < 4; i++) {
            const int row = row0 + wm + i * 16 + cr;
            #pragma unroll
            for (int r = 0; r < 4; r++)
                C[(size_t)(row + r) * M_DIM + col] = acc[i][j][r];
        }
    }
}

// ---------------- Kernel 3: per-row stats + softmax gather + fallbacks ----------------
#define LISTCAP 512

__device__ inline float wred_sum(float v) {
    #pragma unroll
    for (int o = 32; o > 0; o >>= 1) v += __shfl_down(v, o, 64);
    return v;
}
__device__ inline float wred_max(float v) {
    #pragma unroll
    for (int o = 32; o > 0; o >>= 1) v = fmaxf(v, __shfl_down(v, o, 64));
    return v;
}
__device__ inline int wred_sumi(int v) {
    #pragma unroll
    for (int o = 32; o > 0; o >>= 1) v += __shfl_down(v, o, 64);
    return v;
}
__device__ inline unsigned long long wred_minu64(unsigned long long v) {
    #pragma unroll
    for (int o = 32; o > 0; o >>= 1) {
        unsigned long long w = __shfl_down(v, o, 64);
        v = (w < v) ? w : v;
    }
    return v;
}

__global__ __launch_bounds__(256) void stats_gather(const float* __restrict__ sims,
                                                    const float* __restrict__ T,
                                                    float* __restrict__ out) {
    const int b = blockIdx.x;
    const int tid = threadIdx.x;
    const int lane = tid & 63, wid = tid >> 6;
    __shared__ float row[M_DIM];          // 32 KB
    __shared__ float rf[4], rg[4];
    __shared__ int ri[4];
    __shared__ unsigned long long ru[4];
    __shared__ int   lidx[LISTCAP];
    __shared__ float lw[LISTCAP];
    __shared__ int   lcnt_sh;

    const float4* srow = (const float4*)(sims + (size_t)b * M_DIM);
    float4* row4 = (float4*)row;
    for (int i = tid; i < M_DIM / 4; i += 256) row4[i] = srow[i];
    if (tid == 0) lcnt_sh = 0;
    __syncthreads();

    // ---- phase 1: cnt, masked sum, masked max ----
    float psum = 0.f, pmax = -1e30f;
    int pcnt = 0;
    for (int i = tid; i < M_DIM; i += 256) {
        float s = row[i];
        if (s > SIM_T) { pcnt++; psum += s; pmax = fmaxf(pmax, s); }
    }
    psum = wred_sum(psum); pmax = wred_max(pmax); pcnt = wred_sumi(pcnt);
    if (lane == 0) { rf[wid] = psum; rg[wid] = pmax; ri[wid] = pcnt; }
    __syncthreads();
    const int cnt = ri[0] + ri[1] + ri[2] + ri[3];
    const float mean = (rf[0] + rf[1] + rf[2] + rf[3]) / (float)max(cnt, 1);
    const float mx = fmaxf(fmaxf(rg[0], rg[1]), fmaxf(rg[2], rg[3]));
    __syncthreads();

    // ---- phase 2: masked var + argmin|s-mean| (first index wins ties) ----
    float pvar = 0.f, pbest = 1e30f;
    int pbi = 0x7fffffff;
    for (int i = tid; i < M_DIM; i += 256) {
        float s = row[i];
        if (s > SIM_T) { float d = s - mean; pvar += d * d; }
        float v = fabsf(s - mean);
        if (v < pbest) { pbest = v; pbi = i; }
    }
    pvar = wred_sum(pvar);
    unsigned long long key = ((unsigned long long)__float_as_uint(pbest) << 32) | (unsigned)pbi;
    key = wred_minu64(key);
    if (lane == 0) { rf[wid] = pvar; ru[wid] = key; }
    __syncthreads();
    const float var = (rf[0] + rf[1] + rf[2] + rf[3]) / (float)max(cnt, 1);
    const float dyn = mean - ALPHA_C * sqrtf(var);
    unsigned long long k0 = ru[0], k1 = ru[1], k2 = ru[2], k3 = ru[3];
    unsigned long long kb = k0 < k1 ? k0 : k1;
    unsigned long long kc = k2 < k3 ? k2 : k3;
    const int closest = (int)(unsigned)((kb < kc ? kb : kc) & 0xffffffffull);
    __syncthreads();

    // ---- phase 3: final count, softmax denom, compact survivor list ----
    float pden = 0.f;
    int pf = 0;
    for (int i = tid; i < M_DIM; i += 256) {
        float s = row[i];
        if (s > SIM_T && s > dyn) {
            float e = expf(s - mx);
            pden += e; pf++;
            int pos = atomicAdd(&lcnt_sh, 1);
            if (pos < LISTCAP) { lidx[pos] = i; lw[pos] = e; }
        }
    }
    pden = wred_sum(pden); pf = wred_sumi(pf);
    if (lane == 0) { rf[wid] = pden; ri[wid] = pf; }
    __syncthreads();
    const float denom = rf[0] + rf[1] + rf[2] + rf[3];
    const int fcnt = ri[0] + ri[1] + ri[2] + ri[3];
    __syncthreads();

    // ---- phase 4: weighted gather / fallbacks ----
    const float4* T4 = (const float4*)T;
    float4 a0 = make_float4(0.f, 0.f, 0.f, 0.f);
    float4 a1 = make_float4(0.f, 0.f, 0.f, 0.f);
    if (cnt == 0) {
    } else if (fcnt == 0) {
        a0 = T4[(size_t)closest * (D_DIM / 4) + tid];
        a1 = T4[(size_t)closest * (D_DIM / 4) + tid + 256];
    } else {
        const float rden = 1.0f / denom;
        if (fcnt <= LISTCAP) {
            for (int k = 0; k < fcnt; k++) {
                int m = lidx[k];
                float w = lw[k] * rden;
                float4 t0 = T4[(size_t)m * (D_DIM / 4) + tid];
                float4 t1 = T4[(size_t)m * (D_DIM / 4) + tid + 256];
                a0.x += w * t0.x; a0.y += w * t0.y; a0.z += w * t0.z; a0.w += w * t0.w;
                a1.x += w * t1.x; a1.y += w * t1.y; a1.z += w * t1.z; a1.w += w * t1.w;
            }
        } else {
            for (int m = 0; m < M_DIM; m++) {
                float s = row[m];
                if (s > SIM_T && s > dyn) {
                    float w = expf(s - mx) * rden;
                    float4 t0 = T4[(size_t)m * (D_DIM / 4) + tid];
                    float4 t1 = T4[(size_t)m * (D_DIM / 4) + tid + 256];
                    a0.x += w * t0.x; a0.y += w * t0.y; a0.z += w * t0.z; a0.w += w * t0.w;
                    a1.x += w * t1.x; a1.y += w * t1.y; a1.z += w * t1.z; a1.w += w * t1.w;
                }
            }
        }
    }
    float4* out4 = (float4*)(out + (size_t)b * D_DIM);
    out4[tid] = a0;
    out4[tid + 256] = a1;
}

extern "C" void kernel_launch(void* const* d_in, const int* in_sizes, int n_in,
                              void* d_out, int out_size, void* d_ws, size_t ws_size,
                              hipStream_t stream) {
    const float* query = (const float*)d_in[0];
    const float* qset  = (const float*)d_in[1];
    const float* tset  = (const float*)d_in[2];
    float* out = (float*)d_out;

    char* ws = (char*)d_ws;
    size_t off = 0;
    float* sims = (float*)(ws + off); off += (size_t)B_DIM * M_DIM * sizeof(float);   // 64 MB
    ushort* Ah = (ushort*)(ws + off); off += (size_t)B_DIM * D_DIM * sizeof(ushort);
    ushort* Al = (ushort*)(ws + off); off += (size_t)B_DIM * D_DIM * sizeof(ushort);
    ushort* Bh = (ushort*)(ws + off); off += (size_t)M_DIM * D_DIM * sizeof(ushort);
    ushort* Bl = (ushort*)(ws + off); off += (size_t)M_DIM * D_DIM * sizeof(ushort);

    hipLaunchKernelGGL(prep_kernel, dim3(B_DIM + M_DIM), dim3(256), 0, stream,
                       query, qset, Ah, Al, Bh, Bl);
    hipLaunchKernelGGL(gemm_mfma, dim3(M_DIM / 128, B_DIM / 128), dim3(256), 0, stream,
                       Ah, Al, Bh, Bl, sims);
    hipLaunchKernelGGL(stats_gather, dim3(B_DIM), dim3(256), 0, stream,
                       sims, tset, out);
}

// Round 4
// 342.690 us; speedup vs baseline: 1.1465x; 1.1465x over previous
//
#include <hip/hip_runtime.h>
#include <hip/hip_bf16.h>

#define B_DIM 2048
#define M_DIM 8192
#define D_DIM 2048
#define EPSN 1e-8f
#define ALPHA_C 0.5f
#define SIM_T 0.5f

typedef __attribute__((ext_vector_type(8))) short short8;
typedef __attribute__((ext_vector_type(4))) float f32x4;

__device__ inline void split_bf16(float x, ushort& h, ushort& l) {
    __hip_bfloat16 hi = __float2bfloat16(x);          // RNE
    float res = x - __bfloat162float(hi);
    __hip_bfloat16 lo = __float2bfloat16(res);
    h = *(ushort*)&hi; l = *(ushort*)&lo;
}

// ---------------- Kernel 1: normalize row, split fp32 -> bf16 hi/lo ----------------
__global__ __launch_bounds__(256) void prep_kernel(const float* __restrict__ q,
                                                   const float* __restrict__ s,
                                                   ushort* __restrict__ Ah, ushort* __restrict__ Al,
                                                   ushort* __restrict__ Bh, ushort* __restrict__ Bl) {
    const int row = blockIdx.x;
    const int tid = threadIdx.x;
    const float* src;
    ushort *dh, *dl;
    if (row < B_DIM) {
        src = q + (size_t)row * D_DIM;
        dh = Ah + (size_t)row * D_DIM; dl = Al + (size_t)row * D_DIM;
    } else {
        int r = row - B_DIM;
        src = s + (size_t)r * D_DIM;
        dh = Bh + (size_t)r * D_DIM; dl = Bl + (size_t)r * D_DIM;
    }
    const float4* src4 = (const float4*)src;
    float4 v0 = src4[tid];
    float4 v1 = src4[tid + 256];
    float acc = v0.x * v0.x + v0.y * v0.y + v0.z * v0.z + v0.w * v0.w
              + v1.x * v1.x + v1.y * v1.y + v1.z * v1.z + v1.w * v1.w;
    #pragma unroll
    for (int o = 32; o > 0; o >>= 1) acc += __shfl_down(acc, o, 64);
    __shared__ float red[4];
    if ((tid & 63) == 0) red[tid >> 6] = acc;
    __syncthreads();
    const float tot = red[0] + red[1] + red[2] + red[3];
    const float scale = 1.0f / fmaxf(sqrtf(tot), EPSN);

    float xs0[4] = {v0.x * scale, v0.y * scale, v0.z * scale, v0.w * scale};
    float xs1[4] = {v1.x * scale, v1.y * scale, v1.z * scale, v1.w * scale};
    ushort4 h0, l0, h1, l1;
    ushort *hp0 = (ushort*)&h0, *lp0 = (ushort*)&l0, *hp1 = (ushort*)&h1, *lp1 = (ushort*)&l1;
    #pragma unroll
    for (int e = 0; e < 4; e++) { split_bf16(xs0[e], hp0[e], lp0[e]); split_bf16(xs1[e], hp1[e], lp1[e]); }
    ((ushort4*)dh)[tid] = h0;       ((ushort4*)dh)[tid + 256] = h1;
    ((ushort4*)dl)[tid] = l0;       ((ushort4*)dl)[tid + 256] = l1;
}

// ---------------- Kernel 2: split-bf16 MFMA NT GEMM, TK=64, XOR-swizzled LDS ------
// sims[b,m] = (Ah[b]+Al[b]) . (Bh[m]+Bl[m]), dropping lo.lo (error ~2^-18).
// TK=64: LDS row = 128 B = 32 banks, so fragment reads are swizzled:
//   row r's 16B chunk c lives at slot c ^ (r & 7)  -> 2-way (free) instead of 16-way.
// Staging lane L of a 8-row group: row L>>3, stored slot L&7 -> fetch global chunk
//   (L&7) ^ ((L>>3)&7); same 1KB region per wave-load -> coalescing unchanged.
#define TK 64

#define GLOAD_LDS16(g, l) \
    __builtin_amdgcn_global_load_lds((const __attribute__((address_space(1))) void*)(g), \
                                     (__attribute__((address_space(3))) void*)(l), 16, 0, 0)

__global__ __launch_bounds__(256) void gemm_mfma(const ushort* __restrict__ Ah,
                                                 const ushort* __restrict__ Al,
                                                 const ushort* __restrict__ Bh,
                                                 const ushort* __restrict__ Bl,
                                                 float* __restrict__ C) {
    __shared__ ushort sAh[128][TK];   // 16 KB each, 64 KB total
    __shared__ ushort sAl[128][TK];
    __shared__ ushort sBh[128][TK];
    __shared__ ushort sBl[128][TK];

    const int tid = threadIdx.x;
    const int wave = tid >> 6;
    const int lane = tid & 63;
    const int row0 = blockIdx.y * 128;
    const int col0 = blockIdx.x * 128;
    const int wm = (wave >> 1) * 64;
    const int wn = (wave & 1) * 64;

    f32x4 acc[4][4];
    #pragma unroll
    for (int i = 0; i < 4; i++)
        #pragma unroll
        for (int j = 0; j < 4; j++) acc[i][j] = (f32x4){0.f, 0.f, 0.f, 0.f};

    // staging addresses: wave w covers rows [w*32, w*32+32) of each tile,
    // 4 wave-loads per tile (8 rows each: 64 lanes * 16 B = 8 rows * 128 B).
    const int lrow = lane >> 3;                       // 0..7
    const int lke  = ((lane & 7) ^ (lrow & 7)) * 8;   // swizzled global chunk
    const size_t gA = (size_t)(row0 + wave * 32 + lrow) * D_DIM + lke;
    const size_t gB = (size_t)(col0 + wave * 32 + lrow) * D_DIM + lke;
    ushort* lAh = &sAh[wave * 32][0];
    ushort* lAl = &sAl[wave * 32][0];
    ushort* lBh = &sBh[wave * 32][0];
    ushort* lBl = &sBl[wave * 32][0];

    // fragment read swizzle: chunk c = t*4 + (lane>>4), slot = c ^ (fr & 7)
    const int fr  = lane & 15;
    const int c0  = lane >> 4;
    const int off0 = ((c0)     ^ (fr & 7)) * 8;   // k-step 0 element offset
    const int off1 = ((c0 + 4) ^ (fr & 7)) * 8;   // k-step 1 element offset

    for (int k0 = 0; k0 < D_DIM; k0 += TK) {
        __syncthreads();
        #pragma unroll
        for (int j = 0; j < 4; j++) {
            const size_t rj = (size_t)(j * 8) * D_DIM + k0;
            GLOAD_LDS16(Ah + gA + rj, lAh + j * 8 * TK);
            GLOAD_LDS16(Al + gA + rj, lAl + j * 8 * TK);
            GLOAD_LDS16(Bh + gB + rj, lBh + j * 8 * TK);
            GLOAD_LDS16(Bl + gB + rj, lBl + j * 8 * TK);
        }
        __syncthreads();

        #pragma unroll
        for (int t = 0; t < 2; t++) {
            const int off = t ? off1 : off0;
            short8 avh[4], avl[4], bvh[4], bvl[4];
            #pragma unroll
            for (int i = 0; i < 4; i++) {
                avh[i] = *(const short8*)&sAh[0][(wm + i * 16 + fr) * TK + off];
                avl[i] = *(const short8*)&sAl[0][(wm + i * 16 + fr) * TK + off];
                bvh[i] = *(const short8*)&sBh[0][(wn + i * 16 + fr) * TK + off];
                bvl[i] = *(const short8*)&sBl[0][(wn + i * 16 + fr) * TK + off];
            }
            #pragma unroll
            for (int i = 0; i < 4; i++)
                #pragma unroll
                for (int j = 0; j < 4; j++) {
                    acc[i][j] = __builtin_amdgcn_mfma_f32_16x16x32_bf16(avh[i], bvh[j], acc[i][j], 0, 0, 0);
                    acc[i][j] = __builtin_amdgcn_mfma_f32_16x16x32_bf16(avh[i], bvl[j], acc[i][j], 0, 0, 0);
                    acc[i][j] = __builtin_amdgcn_mfma_f32_16x16x32_bf16(avl[i], bvh[j], acc[i][j], 0, 0, 0);
                }
        }
    }

    // epilogue: C/D layout col=lane&15, row=(lane>>4)*4+reg
    const int cn = lane & 15;
    const int cr = (lane >> 4) * 4;
    #pragma unroll
    for (int j = 0; j < 4; j++) {
        const int col = col0 + wn + j * 16 + cn;
        #pragma unroll
        for (int i = 0; i < 4; i++) {
            const int row = row0 + wm + i * 16 + cr;
            #pragma unroll
            for (int r = 0; r < 4; r++)
                C[(size_t)(row + r) * M_DIM + col] = acc[i][j][r];
        }
    }
}

// ---------------- Kernel 3: per-row stats + softmax gather + fallbacks ----------------
#define LISTCAP 512

__device__ inline float wred_sum(float v) {
    #pragma unroll
    for (int o = 32; o > 0; o >>= 1) v += __shfl_down(v, o, 64);
    return v;
}
__device__ inline float wred_max(float v) {
    #pragma unroll
    for (int o = 32; o > 0; o >>= 1) v = fmaxf(v, __shfl_down(v, o, 64));
    return v;
}
__device__ inline int wred_sumi(int v) {
    #pragma unroll
    for (int o = 32; o > 0; o >>= 1) v += __shfl_down(v, o, 64);
    return v;
}
__device__ inline unsigned long long wred_minu64(unsigned long long v) {
    #pragma unroll
    for (int o = 32; o > 0; o >>= 1) {
        unsigned long long w = __shfl_down(v, o, 64);
        v = (w < v) ? w : v;
    }
    return v;
}

__global__ __launch_bounds__(256) void stats_gather(const float* __restrict__ sims,
                                                    const float* __restrict__ T,
                                                    float* __restrict__ out) {
    const int b = blockIdx.x;
    const int tid = threadIdx.x;
    const int lane = tid & 63, wid = tid >> 6;
    __shared__ float row[M_DIM];          // 32 KB
    __shared__ float rf[4], rg[4];
    __shared__ int ri[4];
    __shared__ unsigned long long ru[4];
    __shared__ int   lidx[LISTCAP];
    __shared__ float lw[LISTCAP];
    __shared__ int   lcnt_sh;

    const float4* srow = (const float4*)(sims + (size_t)b * M_DIM);
    float4* row4 = (float4*)row;
    for (int i = tid; i < M_DIM / 4; i += 256) row4[i] = srow[i];
    if (tid == 0) lcnt_sh = 0;
    __syncthreads();

    // ---- phase 1: cnt, masked sum, masked max ----
    float psum = 0.f, pmax = -1e30f;
    int pcnt = 0;
    for (int i = tid; i < M_DIM; i += 256) {
        float s = row[i];
        if (s > SIM_T) { pcnt++; psum += s; pmax = fmaxf(pmax, s); }
    }
    psum = wred_sum(psum); pmax = wred_max(pmax); pcnt = wred_sumi(pcnt);
    if (lane == 0) { rf[wid] = psum; rg[wid] = pmax; ri[wid] = pcnt; }
    __syncthreads();
    const int cnt = ri[0] + ri[1] + ri[2] + ri[3];
    const float mean = (rf[0] + rf[1] + rf[2] + rf[3]) / (float)max(cnt, 1);
    const float mx = fmaxf(fmaxf(rg[0], rg[1]), fmaxf(rg[2], rg[3]));
    __syncthreads();

    // ---- phase 2: masked var + argmin|s-mean| (first index wins ties) ----
    float pvar = 0.f, pbest = 1e30f;
    int pbi = 0x7fffffff;
    for (int i = tid; i < M_DIM; i += 256) {
        float s = row[i];
        if (s > SIM_T) { float d = s - mean; pvar += d * d; }
        float v = fabsf(s - mean);
        if (v < pbest) { pbest = v; pbi = i; }
    }
    pvar = wred_sum(pvar);
    unsigned long long key = ((unsigned long long)__float_as_uint(pbest) << 32) | (unsigned)pbi;
    key = wred_minu64(key);
    if (lane == 0) { rf[wid] = pvar; ru[wid] = key; }
    __syncthreads();
    const float var = (rf[0] + rf[1] + rf[2] + rf[3]) / (float)max(cnt, 1);
    const float dyn = mean - ALPHA_C * sqrtf(var);
    unsigned long long k0 = ru[0], k1 = ru[1], k2 = ru[2], k3 = ru[3];
    unsigned long long kb = k0 < k1 ? k0 : k1;
    unsigned long long kc = k2 < k3 ? k2 : k3;
    const int closest = (int)(unsigned)((kb < kc ? kb : kc) & 0xffffffffull);
    __syncthreads();

    // ---- phase 3: final count, softmax denom, compact survivor list ----
    float pden = 0.f;
    int pf = 0;
    for (int i = tid; i < M_DIM; i += 256) {
        float s = row[i];
        if (s > SIM_T && s > dyn) {
            float e = expf(s - mx);
            pden += e; pf++;
            int pos = atomicAdd(&lcnt_sh, 1);
            if (pos < LISTCAP) { lidx[pos] = i; lw[pos] = e; }
        }
    }
    pden = wred_sum(pden); pf = wred_sumi(pf);
    if (lane == 0) { rf[wid] = pden; ri[wid] = pf; }
    __syncthreads();
    const float denom = rf[0] + rf[1] + rf[2] + rf[3];
    const int fcnt = ri[0] + ri[1] + ri[2] + ri[3];
    __syncthreads();

    // ---- phase 4: weighted gather / fallbacks ----
    const float4* T4 = (const float4*)T;
    float4 a0 = make_float4(0.f, 0.f, 0.f, 0.f);
    float4 a1 = make_float4(0.f, 0.f, 0.f, 0.f);
    if (cnt == 0) {
    } else if (fcnt == 0) {
        a0 = T4[(size_t)closest * (D_DIM / 4) + tid];
        a1 = T4[(size_t)closest * (D_DIM / 4) + tid + 256];
    } else {
        const float rden = 1.0f / denom;
        if (fcnt <= LISTCAP) {
            for (int k = 0; k < fcnt; k++) {
                int m = lidx[k];
                float w = lw[k] * rden;
                float4 t0 = T4[(size_t)m * (D_DIM / 4) + tid];
                float4 t1 = T4[(size_t)m * (D_DIM / 4) + tid + 256];
                a0.x += w * t0.x; a0.y += w * t0.y; a0.z += w * t0.z; a0.w += w * t0.w;
                a1.x += w * t1.x; a1.y += w * t1.y; a1.z += w * t1.z; a1.w += w * t1.w;
            }
        } else {
            for (int m = 0; m < M_DIM; m++) {
                float s = row[m];
                if (s > SIM_T && s > dyn) {
                    float w = expf(s - mx) * rden;
                    float4 t0 = T4[(size_t)m * (D_DIM / 4) + tid];
                    float4 t1 = T4[(size_t)m * (D_DIM / 4) + tid + 256];
                    a0.x += w * t0.x; a0.y += w * t0.y; a0.z += w * t0.z; a0.w += w * t0.w;
                    a1.x += w * t1.x; a1.y += w * t1.y; a1.z += w * t1.z; a1.w += w * t1.w;
                }
            }
        }
    }
    float4* out4 = (float4*)(out + (size_t)b * D_DIM);
    out4[tid] = a0;
    out4[tid + 256] = a1;
}

extern "C" void kernel_launch(void* const* d_in, const int* in_sizes, int n_in,
                              void* d_out, int out_size, void* d_ws, size_t ws_size,
                              hipStream_t stream) {
    const float* query = (const float*)d_in[0];
    const float* qset  = (const float*)d_in[1];
    const float* tset  = (const float*)d_in[2];
    float* out = (float*)d_out;

    char* ws = (char*)d_ws;
    size_t off = 0;
    float* sims = (float*)(ws + off); off += (size_t)B_DIM * M_DIM * sizeof(float);   // 64 MB
    ushort* Ah = (ushort*)(ws + off); off += (size_t)B_DIM * D_DIM * sizeof(ushort);
    ushort* Al = (ushort*)(ws + off); off += (size_t)B_DIM * D_DIM * sizeof(ushort);
    ushort* Bh = (ushort*)(ws + off); off += (size_t)M_DIM * D_DIM * sizeof(ushort);
    ushort* Bl = (ushort*)(ws + off); off += (size_t)M_DIM * D_DIM * sizeof(ushort);

    hipLaunchKernelGGL(prep_kernel, dim3(B_DIM + M_DIM), dim3(256), 0, stream,
                       query, qset, Ah, Al, Bh, Bl);
    hipLaunchKernelGGL(gemm_mfma, dim3(M_DIM / 128, B_DIM / 128), dim3(256), 0, stream,
                       Ah, Al, Bh, Bl, sims);
    hipLaunchKernelGGL(stats_gather, dim3(B_DIM), dim3(256), 0, stream,
                       sims, tset, out);
}

// Round 5
// 262.592 us; speedup vs baseline: 1.4963x; 1.3050x over previous
//
#include <hip/hip_runtime.h>
#include <hip/hip_bf16.h>

#define B_DIM 2048
#define M_DIM 8192
#define D_DIM 2048
#define EPSN 1e-8f
#define ALPHA_C 0.5f
#define SIM_T 0.5f
#define SCREEN_T 0.49f   // bf16-GEMM screen: worst-case |err| <= 0.004, so every
                         // true sim > 0.5 lands > 0.496 > 0.49; junk (< 0.486) is
                         // re-checked exactly and discarded.
#define CAP 2048         // per-row candidate cap (expected ~4, Poisson; 2048 is unreachable)

typedef __attribute__((ext_vector_type(8))) short short8;
typedef __attribute__((ext_vector_type(4))) float f32x4;

// ---------------- Kernel 1: normalize row -> bf16 (RNE); zero candidate counters --
__global__ __launch_bounds__(256) void prep_kernel(const float* __restrict__ q,
                                                   const float* __restrict__ s,
                                                   ushort* __restrict__ Abf,
                                                   ushort* __restrict__ Bbf,
                                                   float* __restrict__ rq,
                                                   float* __restrict__ rs,
                                                   int* __restrict__ ccnt) {
    const int row = blockIdx.x;
    const int tid = threadIdx.x;
    const float* src;
    ushort* dst;
    float* rdst;
    if (row < B_DIM) {
        src = q + (size_t)row * D_DIM; dst = Abf + (size_t)row * D_DIM; rdst = rq + row;
        if (tid == 0) ccnt[row] = 0;            // zero per-row candidate counter
    } else {
        int r = row - B_DIM;
        src = s + (size_t)r * D_DIM; dst = Bbf + (size_t)r * D_DIM; rdst = rs + r;
    }
    const float4* src4 = (const float4*)src;
    float4 v0 = src4[tid];
    float4 v1 = src4[tid + 256];
    float acc = v0.x * v0.x + v0.y * v0.y + v0.z * v0.z + v0.w * v0.w
              + v1.x * v1.x + v1.y * v1.y + v1.z * v1.z + v1.w * v1.w;
    #pragma unroll
    for (int o = 32; o > 0; o >>= 1) acc += __shfl_down(acc, o, 64);
    __shared__ float red[4];
    if ((tid & 63) == 0) red[tid >> 6] = acc;
    __syncthreads();
    const float tot = red[0] + red[1] + red[2] + red[3];
    const float scale = 1.0f / fmaxf(sqrtf(tot), EPSN);
    if (tid == 0) *rdst = scale;

    float xs0[4] = {v0.x * scale, v0.y * scale, v0.z * scale, v0.w * scale};
    float xs1[4] = {v1.x * scale, v1.y * scale, v1.z * scale, v1.w * scale};
    ushort4 h0, h1;
    ushort *hp0 = (ushort*)&h0, *hp1 = (ushort*)&h1;
    #pragma unroll
    for (int e = 0; e < 4; e++) {
        __hip_bfloat16 b0 = __float2bfloat16(xs0[e]);
        __hip_bfloat16 b1 = __float2bfloat16(xs1[e]);
        hp0[e] = *(ushort*)&b0; hp1[e] = *(ushort*)&b1;
    }
    ((ushort4*)dst)[tid] = h0;
    ((ushort4*)dst)[tid + 256] = h1;
}

// ---------------- Kernel 2: bf16 NT GEMM screen, TK=64, XOR-swizzled LDS ----------
// No C matrix: epilogue pushes (row -> col) candidates where acc > SCREEN_T.
#define TK 64

#define GLOAD_LDS16(g, l) \
    __builtin_amdgcn_global_load_lds((const __attribute__((address_space(1))) void*)(g), \
                                     (__attribute__((address_space(3))) void*)(l), 16, 0, 0)

__global__ __launch_bounds__(256) void gemm_mfma(const ushort* __restrict__ Abf,
                                                 const ushort* __restrict__ Bbf,
                                                 int* __restrict__ ccnt,
                                                 int* __restrict__ cidx) {
    __shared__ ushort sA[128][TK];   // 16 KB each, 32 KB total
    __shared__ ushort sB[128][TK];

    const int tid = threadIdx.x;
    const int wave = tid >> 6;
    const int lane = tid & 63;
    const int row0 = blockIdx.y * 128;
    const int col0 = blockIdx.x * 128;
    const int wm = (wave >> 1) * 64;
    const int wn = (wave & 1) * 64;

    f32x4 acc[4][4];
    #pragma unroll
    for (int i = 0; i < 4; i++)
        #pragma unroll
        for (int j = 0; j < 4; j++) acc[i][j] = (f32x4){0.f, 0.f, 0.f, 0.f};

    // staging: wave w covers rows [w*32, w*32+32) of each tile; 4 wave-loads/tile
    // (8 rows each). XOR swizzle: row r's 16B chunk c stored at slot c ^ (r & 7).
    const int lrow = lane >> 3;                       // 0..7
    const int lke  = ((lane & 7) ^ (lrow & 7)) * 8;   // swizzled global chunk
    const size_t gA = (size_t)(row0 + wave * 32 + lrow) * D_DIM + lke;
    const size_t gB = (size_t)(col0 + wave * 32 + lrow) * D_DIM + lke;
    ushort* lA = &sA[wave * 32][0];
    ushort* lB = &sB[wave * 32][0];

    const int fr  = lane & 15;
    const int c0  = lane >> 4;
    const int off0 = ((c0)     ^ (fr & 7)) * 8;
    const int off1 = ((c0 + 4) ^ (fr & 7)) * 8;

    for (int k0 = 0; k0 < D_DIM; k0 += TK) {
        __syncthreads();
        #pragma unroll
        for (int j = 0; j < 4; j++) {
            const size_t rj = (size_t)(j * 8) * D_DIM + k0;
            GLOAD_LDS16(Abf + gA + rj, lA + j * 8 * TK);
            GLOAD_LDS16(Bbf + gB + rj, lB + j * 8 * TK);
        }
        __syncthreads();

        #pragma unroll
        for (int t = 0; t < 2; t++) {
            const int off = t ? off1 : off0;
            short8 av[4], bv[4];
            #pragma unroll
            for (int i = 0; i < 4; i++) {
                av[i] = *(const short8*)&sA[0][(wm + i * 16 + fr) * TK + off];
                bv[i] = *(const short8*)&sB[0][(wn + i * 16 + fr) * TK + off];
            }
            #pragma unroll
            for (int i = 0; i < 4; i++)
                #pragma unroll
                for (int j = 0; j < 4; j++)
                    acc[i][j] = __builtin_amdgcn_mfma_f32_16x16x32_bf16(av[i], bv[j], acc[i][j], 0, 0, 0);
        }
    }

    // epilogue screen: C/D layout col=lane&15, row=(lane>>4)*4+reg
    const int cn = lane & 15;
    const int cr = (lane >> 4) * 4;
    #pragma unroll
    for (int j = 0; j < 4; j++) {
        const int col = col0 + wn + j * 16 + cn;
        #pragma unroll
        for (int i = 0; i < 4; i++) {
            const int row = row0 + wm + i * 16 + cr;
            #pragma unroll
            for (int r = 0; r < 4; r++) {
                if (acc[i][j][r] > SCREEN_T) {
                    int pos = atomicAdd(&ccnt[row + r], 1);
                    if (pos < CAP) cidx[(size_t)(row + r) * CAP + pos] = col;
                }
            }
        }
    }
}

// ---------------- Kernel 3: exact rescue + stats + softmax gather + fallbacks -----
__device__ inline float wred_sum(float v) {
    #pragma unroll
    for (int o = 32; o > 0; o >>= 1) v += __shfl_down(v, o, 64);
    return v;
}
__device__ inline float wred_max(float v) {
    #pragma unroll
    for (int o = 32; o > 0; o >>= 1) v = fmaxf(v, __shfl_down(v, o, 64));
    return v;
}
__device__ inline int wred_sumi(int v) {
    #pragma unroll
    for (int o = 32; o > 0; o >>= 1) v += __shfl_down(v, o, 64);
    return v;
}
__device__ inline unsigned long long wred_minu64(unsigned long long v) {
    #pragma unroll
    for (int o = 32; o > 0; o >>= 1) {
        unsigned long long w = __shfl_down(v, o, 64);
        v = (w < v) ? w : v;
    }
    return v;
}

__global__ __launch_bounds__(256) void stats_gather(const float* __restrict__ q,
                                                    const float* __restrict__ s,
                                                    const float* __restrict__ T,
                                                    const float* __restrict__ rq,
                                                    const float* __restrict__ rs,
                                                    const int* __restrict__ ccnt,
                                                    const int* __restrict__ cidx,
                                                    float* __restrict__ out) {
    const int b = blockIdx.x;
    const int tid = threadIdx.x;
    const int lane = tid & 63, wave = tid >> 6;
    __shared__ float qrow[D_DIM];         // 8 KB, normalized query row
    __shared__ float cval[CAP];           // 8 KB, exact sims of candidates
    __shared__ float rf[4], rg[4];
    __shared__ int ri[4];
    __shared__ unsigned long long ru[4];

    const int nc = min(ccnt[b], CAP);
    const float qscale = rq[b];

    // load + normalize query row into LDS
    {
        const float4* q4 = (const float4*)(q + (size_t)b * D_DIM);
        float4 v0 = q4[tid], v1 = q4[tid + 256];
        v0.x *= qscale; v0.y *= qscale; v0.z *= qscale; v0.w *= qscale;
        v1.x *= qscale; v1.y *= qscale; v1.z *= qscale; v1.w *= qscale;
        ((float4*)qrow)[tid] = v0;
        ((float4*)qrow)[tid + 256] = v1;
    }
    __syncthreads();

    // exact fp32 dot per candidate: one wave per candidate, 4-way parallel
    const int* myidx = cidx + (size_t)b * CAP;
    for (int k = wave; k < nc; k += 4) {
        const int m = myidx[k];
        const float4* s4 = (const float4*)(s + (size_t)m * D_DIM);
        const float4* q4 = (const float4*)qrow;
        float p = 0.f;
        #pragma unroll
        for (int e = 0; e < 8; e++) {
            float4 sv = s4[lane + e * 64];
            float4 qv = q4[lane + e * 64];
            p = fmaf(sv.x, qv.x, p); p = fmaf(sv.y, qv.y, p);
            p = fmaf(sv.z, qv.z, p); p = fmaf(sv.w, qv.w, p);
        }
        p = wred_sum(p);
        if (lane == 0) cval[k] = p * rs[m];
    }
    __syncthreads();

    // ---- phase 1: cnt, masked sum, masked max (exact values, strict > 0.5) ----
    float psum = 0.f, pmax = -1e30f;
    int pcnt = 0;
    for (int k = tid; k < nc; k += 256) {
        float v = cval[k];
        if (v > SIM_T) { pcnt++; psum += v; pmax = fmaxf(pmax, v); }
    }
    psum = wred_sum(psum); pmax = wred_max(pmax); pcnt = wred_sumi(pcnt);
    if (lane == 0) { rf[wave] = psum; rg[wave] = pmax; ri[wave] = pcnt; }
    __syncthreads();
    const int cnt = ri[0] + ri[1] + ri[2] + ri[3];
    const float mean = (rf[0] + rf[1] + rf[2] + rf[3]) / (float)max(cnt, 1);
    const float mx = fmaxf(fmaxf(rg[0], rg[1]), fmaxf(rg[2], rg[3]));
    __syncthreads();

    // ---- phase 2: masked var + argmin|s-mean| over candidates ----
    // Valid: for cnt>0, the masked minimum (dist < mean-0.5) strictly beats every
    // non-candidate (true sim <= 0.499 -> dist > mean-0.499). Ties broken by m.
    float pvar = 0.f;
    unsigned long long pkey = 0xffffffffffffffffull;
    for (int k = tid; k < nc; k += 256) {
        float v = cval[k];
        if (v > SIM_T) { float d = v - mean; pvar += d * d; }
        unsigned long long kk = ((unsigned long long)__float_as_uint(fabsf(v - mean)) << 32)
                              | (unsigned)myidx[k];
        pkey = (kk < pkey) ? kk : pkey;
    }
    pvar = wred_sum(pvar); pkey = wred_minu64(pkey);
    if (lane == 0) { rf[wave] = pvar; ru[wave] = pkey; }
    __syncthreads();
    const float var = (rf[0] + rf[1] + rf[2] + rf[3]) / (float)max(cnt, 1);
    const float dyn = mean - ALPHA_C * sqrtf(var);
    unsigned long long k0 = ru[0] < ru[1] ? ru[0] : ru[1];
    unsigned long long k1 = ru[2] < ru[3] ? ru[2] : ru[3];
    const int closest = (int)(unsigned)((k0 < k1 ? k0 : k1) & 0xffffffffull);
    __syncthreads();

    // ---- phase 3: final count + softmax denom ----
    float pden = 0.f;
    int pf = 0;
    for (int k = tid; k < nc; k += 256) {
        float v = cval[k];
        if (v > SIM_T && v > dyn) { pden += expf(v - mx); pf++; }
    }
    pden = wred_sum(pden); pf = wred_sumi(pf);
    if (lane == 0) { rf[wave] = pden; ri[wave] = pf; }
    __syncthreads();
    const float denom = rf[0] + rf[1] + rf[2] + rf[3];
    const int fcnt = ri[0] + ri[1] + ri[2] + ri[3];

    // ---- phase 4: weighted gather / fallbacks ----
    const float4* T4 = (const float4*)T;
    float4 a0 = make_float4(0.f, 0.f, 0.f, 0.f);
    float4 a1 = make_float4(0.f, 0.f, 0.f, 0.f);
    if (cnt == 0) {
        // zeros (first mask empty)
    } else if (fcnt == 0) {
        a0 = T4[(size_t)closest * (D_DIM / 4) + tid];
        a1 = T4[(size_t)closest * (D_DIM / 4) + tid + 256];
    } else {
        const float rden = 1.0f / denom;
        for (int k = 0; k < nc; k++) {
            float v = cval[k];
            if (v > SIM_T && v > dyn) {
                const int m = myidx[k];
                const float w = expf(v - mx) * rden;
                float4 t0 = T4[(size_t)m * (D_DIM / 4) + tid];
                float4 t1 = T4[(size_t)m * (D_DIM / 4) + tid + 256];
                a0.x += w * t0.x; a0.y += w * t0.y; a0.z += w * t0.z; a0.w += w * t0.w;
                a1.x += w * t1.x; a1.y += w * t1.y; a1.z += w * t1.z; a1.w += w * t1.w;
            }
        }
    }
    float4* out4 = (float4*)(out + (size_t)b * D_DIM);
    out4[tid] = a0;
    out4[tid + 256] = a1;
}

extern "C" void kernel_launch(void* const* d_in, const int* in_sizes, int n_in,
                              void* d_out, int out_size, void* d_ws, size_t ws_size,
                              hipStream_t stream) {
    const float* query = (const float*)d_in[0];
    const float* qset  = (const float*)d_in[1];
    const float* tset  = (const float*)d_in[2];
    float* out = (float*)d_out;

    char* ws = (char*)d_ws;
    size_t off = 0;
    ushort* Abf = (ushort*)(ws + off); off += (size_t)B_DIM * D_DIM * sizeof(ushort);  // 8 MB
    ushort* Bbf = (ushort*)(ws + off); off += (size_t)M_DIM * D_DIM * sizeof(ushort);  // 32 MB
    float* rq   = (float*)(ws + off);  off += B_DIM * sizeof(float);
    float* rs   = (float*)(ws + off);  off += M_DIM * sizeof(float);
    int* ccnt   = (int*)(ws + off);    off += B_DIM * sizeof(int);
    int* cidx   = (int*)(ws + off);    off += (size_t)B_DIM * CAP * sizeof(int);       // 16 MB

    hipLaunchKernelGGL(prep_kernel, dim3(B_DIM + M_DIM), dim3(256), 0, stream,
                       query, qset, Abf, Bbf, rq, rs, ccnt);
    hipLaunchKernelGGL(gemm_mfma, dim3(M_DIM / 128, B_DIM / 128), dim3(256), 0, stream,
                       Abf, Bbf, ccnt, cidx);
    hipLaunchKernelGGL(stats_gather, dim3(B_DIM), dim3(256), 0, stream,
                       query, qset, tset, rq, rs, ccnt, cidx, out);
}

// Round 6
// 240.242 us; speedup vs baseline: 1.6355x; 1.0930x over previous
//
#include <hip/hip_runtime.h>
#include <hip/hip_bf16.h>
#include <hip/hip_fp8.h>

#define B_DIM 2048
#define M_DIM 8192
#define D_DIM 2048
#define EPSN 1e-8f
#define ALPHA_C 0.5f
#define SIM_T 0.5f
#define SCREEN_T 0.35f   // fp8 screen: dot error worst ~0.02; matched (true>0.5)
                         // land >0.45; unmatched (true<0.13) land <0.2. Junk in
                         // (0.35,0.5] true-range is discarded by exact rescue.
#define CAP 2048

typedef __attribute__((ext_vector_type(4))) float f32x4;

// ---------------- Kernel 1: normalize row -> fp8 e4m3 (OCP); zero counters -------
__global__ __launch_bounds__(256) void prep_kernel(const float* __restrict__ q,
                                                   const float* __restrict__ s,
                                                   unsigned char* __restrict__ A8,
                                                   unsigned char* __restrict__ B8,
                                                   float* __restrict__ rq,
                                                   float* __restrict__ rs,
                                                   int* __restrict__ ccnt) {
    const int row = blockIdx.x;
    const int tid = threadIdx.x;
    const float* src;
    unsigned char* dst;
    float* rdst;
    if (row < B_DIM) {
        src = q + (size_t)row * D_DIM; dst = A8 + (size_t)row * D_DIM; rdst = rq + row;
        if (tid == 0) ccnt[row] = 0;
    } else {
        int r = row - B_DIM;
        src = s + (size_t)r * D_DIM; dst = B8 + (size_t)r * D_DIM; rdst = rs + r;
    }
    const float4* src4 = (const float4*)src;
    float4 v0 = src4[2 * tid];       // 8 contiguous elems per thread
    float4 v1 = src4[2 * tid + 1];
    float acc = v0.x * v0.x + v0.y * v0.y + v0.z * v0.z + v0.w * v0.w
              + v1.x * v1.x + v1.y * v1.y + v1.z * v1.z + v1.w * v1.w;
    #pragma unroll
    for (int o = 32; o > 0; o >>= 1) acc += __shfl_down(acc, o, 64);
    __shared__ float red[4];
    if ((tid & 63) == 0) red[tid >> 6] = acc;
    __syncthreads();
    const float tot = red[0] + red[1] + red[2] + red[3];
    const float scale = 1.0f / fmaxf(sqrtf(tot), EPSN);
    if (tid == 0) *rdst = scale;

    float xs[8] = {v0.x * scale, v0.y * scale, v0.z * scale, v0.w * scale,
                   v1.x * scale, v1.y * scale, v1.z * scale, v1.w * scale};
    union { unsigned char b[8]; uint2 u; } pk;
    #pragma unroll
    for (int e = 0; e < 8; e++) {
        __hip_fp8_e4m3 f(xs[e]);                // OCP e4m3fn
        pk.b[e] = f.__x;
    }
    ((uint2*)dst)[tid] = pk.u;
}

// ---------------- Kernel 2: fp8 NT GEMM screen, TK=128, XOR-swizzled LDS ---------
// Screen values only; epilogue pushes (row -> col) candidates where acc > SCREEN_T.
#define TK 128   // bytes per LDS row (fp8); 32 banks/row -> swizzle mandatory

#define GLOAD_LDS16(g, l) \
    __builtin_amdgcn_global_load_lds((const __attribute__((address_space(1))) void*)(g), \
                                     (__attribute__((address_space(3))) void*)(l), 16, 0, 0)

__global__ __launch_bounds__(256) void gemm_screen(const unsigned char* __restrict__ A8,
                                                   const unsigned char* __restrict__ B8,
                                                   int* __restrict__ ccnt,
                                                   int* __restrict__ cidx) {
    __shared__ unsigned char sA[128][TK];   // 16 KB each, 32 KB total
    __shared__ unsigned char sB[128][TK];

    const int tid = threadIdx.x;
    const int wave = tid >> 6;
    const int lane = tid & 63;
    const int row0 = blockIdx.y * 128;
    const int col0 = blockIdx.x * 128;
    const int wm = (wave >> 1) * 64;
    const int wn = (wave & 1) * 64;

    f32x4 acc[4][4];
    #pragma unroll
    for (int i = 0; i < 4; i++)
        #pragma unroll
        for (int j = 0; j < 4; j++) acc[i][j] = (f32x4){0.f, 0.f, 0.f, 0.f};

    // staging: 1 wave-load = 64 lanes * 16 B = 8 rows * 128 B. Wave w covers rows
    // [w*32, w*32+32): 4 loads per array. Swizzle: row r's 16B chunk c at slot
    // c ^ (r & 7); lane L writes slot L&7 of row L>>3 -> fetch global chunk
    // (L&7) ^ ((L>>3)&7).
    const int lrow = lane >> 3;                            // 0..7
    const int gc   = (lane & 7) ^ (lrow & 7);              // swizzled global chunk
    const size_t gA = (size_t)(row0 + wave * 32 + lrow) * D_DIM + gc * 16;
    const size_t gB = (size_t)(col0 + wave * 32 + lrow) * D_DIM + gc * 16;

    // fragment read: lane holds 8 fp8, k = (lane>>4)*8 + j (same mapping as bf16
    // 16x16x32). Byte offset in k-step t: t*32 + q*8 -> chunk c = t*2 + (q>>1),
    // half h = q&1; LDS offset = (c ^ (fr&7))*16 + h*8.
    const int fr = lane & 15;
    const int q_ = lane >> 4;
    const int h8 = (q_ & 1) * 8;
    const int cq = q_ >> 1;

    for (int k0 = 0; k0 < D_DIM; k0 += TK) {
        __syncthreads();
        #pragma unroll
        for (int j = 0; j < 4; j++) {
            const size_t rj = (size_t)(j * 8) * D_DIM + k0;
            GLOAD_LDS16(A8 + gA + rj, &sA[wave * 32 + j * 8][0]);
            GLOAD_LDS16(B8 + gB + rj, &sB[wave * 32 + j * 8][0]);
        }
        __syncthreads();

        #pragma unroll
        for (int t = 0; t < 4; t++) {
            const int off = ((t * 2 + cq) ^ (fr & 7)) * 16 + h8;
            long av[4], bv[4];
            #pragma unroll
            for (int i = 0; i < 4; i++) {
                av[i] = *(const long*)&sA[wm + i * 16 + fr][off];
                bv[i] = *(const long*)&sB[wn + i * 16 + fr][off];
            }
            #pragma unroll
            for (int i = 0; i < 4; i++)
                #pragma unroll
                for (int j = 0; j < 4; j++)
                    acc[i][j] = __builtin_amdgcn_mfma_f32_16x16x32_fp8_fp8(av[i], bv[j], acc[i][j], 0, 0, 0);
        }
    }

    // epilogue screen: C/D layout col=lane&15, row=(lane>>4)*4+reg
    const int cn = lane & 15;
    const int cr = (lane >> 4) * 4;
    #pragma unroll
    for (int j = 0; j < 4; j++) {
        const int col = col0 + wn + j * 16 + cn;
        #pragma unroll
        for (int i = 0; i < 4; i++) {
            const int row = row0 + wm + i * 16 + cr;
            #pragma unroll
            for (int r = 0; r < 4; r++) {
                if (acc[i][j][r] > SCREEN_T) {
                    int pos = atomicAdd(&ccnt[row + r], 1);
                    if (pos < CAP) cidx[(size_t)(row + r) * CAP + pos] = col;
                }
            }
        }
    }
}

// ---------------- Kernel 3: exact rescue + stats + softmax gather + fallbacks -----
__device__ inline float wred_sum(float v) {
    #pragma unroll
    for (int o = 32; o > 0; o >>= 1) v += __shfl_down(v, o, 64);
    return v;
}
__device__ inline float wred_max(float v) {
    #pragma unroll
    for (int o = 32; o > 0; o >>= 1) v = fmaxf(v, __shfl_down(v, o, 64));
    return v;
}
__device__ inline int wred_sumi(int v) {
    #pragma unroll
    for (int o = 32; o > 0; o >>= 1) v += __shfl_down(v, o, 64);
    return v;
}
__device__ inline unsigned long long wred_minu64(unsigned long long v) {
    #pragma unroll
    for (int o = 32; o > 0; o >>= 1) {
        unsigned long long w = __shfl_down(v, o, 64);
        v = (w < v) ? w : v;
    }
    return v;
}

__global__ __launch_bounds__(256) void stats_gather(const float* __restrict__ q,
                                                    const float* __restrict__ s,
                                                    const float* __restrict__ T,
                                                    const float* __restrict__ rq,
                                                    const float* __restrict__ rs,
                                                    const int* __restrict__ ccnt,
                                                    const int* __restrict__ cidx,
                                                    float* __restrict__ out) {
    const int b = blockIdx.x;
    const int tid = threadIdx.x;
    const int lane = tid & 63, wave = tid >> 6;
    __shared__ float qrow[D_DIM];         // 8 KB, normalized query row
    __shared__ float cval[CAP];           // 8 KB, exact sims of candidates
    __shared__ float rf[4], rg[4];
    __shared__ int ri[4];
    __shared__ unsigned long long ru[4];

    const int nc = min(ccnt[b], CAP);
    const float qscale = rq[b];

    {
        const float4* q4 = (const float4*)(q + (size_t)b * D_DIM);
        float4 v0 = q4[tid], v1 = q4[tid + 256];
        v0.x *= qscale; v0.y *= qscale; v0.z *= qscale; v0.w *= qscale;
        v1.x *= qscale; v1.y *= qscale; v1.z *= qscale; v1.w *= qscale;
        ((float4*)qrow)[tid] = v0;
        ((float4*)qrow)[tid + 256] = v1;
    }
    __syncthreads();

    // exact fp32 dot per candidate: one wave per candidate
    const int* myidx = cidx + (size_t)b * CAP;
    for (int k = wave; k < nc; k += 4) {
        const int m = myidx[k];
        const float4* s4 = (const float4*)(s + (size_t)m * D_DIM);
        const float4* q4 = (const float4*)qrow;
        float p = 0.f;
        #pragma unroll
        for (int e = 0; e < 8; e++) {
            float4 sv = s4[lane + e * 64];
            float4 qv = q4[lane + e * 64];
            p = fmaf(sv.x, qv.x, p); p = fmaf(sv.y, qv.y, p);
            p = fmaf(sv.z, qv.z, p); p = fmaf(sv.w, qv.w, p);
        }
        p = wred_sum(p);
        if (lane == 0) cval[k] = p * rs[m];
    }
    __syncthreads();

    // ---- phase 1: cnt, masked sum, masked max (exact, strict > 0.5) ----
    float psum = 0.f, pmax = -1e30f;
    int pcnt = 0;
    for (int k = tid; k < nc; k += 256) {
        float v = cval[k];
        if (v > SIM_T) { pcnt++; psum += v; pmax = fmaxf(pmax, v); }
    }
    psum = wred_sum(psum); pmax = wred_max(pmax); pcnt = wred_sumi(pcnt);
    if (lane == 0) { rf[wave] = psum; rg[wave] = pmax; ri[wave] = pcnt; }
    __syncthreads();
    const int cnt = ri[0] + ri[1] + ri[2] + ri[3];
    const float mean = (rf[0] + rf[1] + rf[2] + rf[3]) / (float)max(cnt, 1);
    const float mx = fmaxf(fmaxf(rg[0], rg[1]), fmaxf(rg[2], rg[3]));
    __syncthreads();

    // ---- phase 2: masked var + argmin|s-mean| over candidates ----
    // Valid: masked min distance <= mean - smin < mean - 0.5 <= any non-candidate
    // distance (true sim <= 0.5); first-index tie-break = smallest m.
    float pvar = 0.f;
    unsigned long long pkey = 0xffffffffffffffffull;
    for (int k = tid; k < nc; k += 256) {
        float v = cval[k];
        if (v > SIM_T) { float d = v - mean; pvar += d * d; }
        unsigned long long kk = ((unsigned long long)__float_as_uint(fabsf(v - mean)) << 32)
                              | (unsigned)myidx[k];
        pkey = (kk < pkey) ? kk : pkey;
    }
    pvar = wred_sum(pvar); pkey = wred_minu64(pkey);
    if (lane == 0) { rf[wave] = pvar; ru[wave] = pkey; }
    __syncthreads();
    const float var = (rf[0] + rf[1] + rf[2] + rf[3]) / (float)max(cnt, 1);
    const float dyn = mean - ALPHA_C * sqrtf(var);
    unsigned long long k0 = ru[0] < ru[1] ? ru[0] : ru[1];
    unsigned long long k1 = ru[2] < ru[3] ? ru[2] : ru[3];
    const int closest = (int)(unsigned)((k0 < k1 ? k0 : k1) & 0xffffffffull);
    __syncthreads();

    // ---- phase 3: final count + softmax denom ----
    float pden = 0.f;
    int pf = 0;
    for (int k = tid; k < nc; k += 256) {
        float v = cval[k];
        if (v > SIM_T && v > dyn) { pden += expf(v - mx); pf++; }
    }
    pden = wred_sum(pden); pf = wred_sumi(pf);
    if (lane == 0) { rf[wave] = pden; ri[wave] = pf; }
    __syncthreads();
    const float denom = rf[0] + rf[1] + rf[2] + rf[3];
    const int fcnt = ri[0] + ri[1] + ri[2] + ri[3];

    // ---- phase 4: weighted gather / fallbacks ----
    const float4* T4 = (const float4*)T;
    float4 a0 = make_float4(0.f, 0.f, 0.f, 0.f);
    float4 a1 = make_float4(0.f, 0.f, 0.f, 0.f);
    if (cnt == 0) {
        // zeros (first mask empty)
    } else if (fcnt == 0) {
        a0 = T4[(size_t)closest * (D_DIM / 4) + tid];
        a1 = T4[(size_t)closest * (D_DIM / 4) + tid + 256];
    } else {
        const float rden = 1.0f / denom;
        for (int k = 0; k < nc; k++) {
            float v = cval[k];
            if (v > SIM_T && v > dyn) {
                const int m = myidx[k];
                const float w = expf(v - mx) * rden;
                float4 t0 = T4[(size_t)m * (D_DIM / 4) + tid];
                float4 t1 = T4[(size_t)m * (D_DIM / 4) + tid + 256];
                a0.x += w * t0.x; a0.y += w * t0.y; a0.z += w * t0.z; a0.w += w * t0.w;
                a1.x += w * t1.x; a1.y += w * t1.y; a1.z += w * t1.z; a1.w += w * t1.w;
            }
        }
    }
    float4* out4 = (float4*)(out + (size_t)b * D_DIM);
    out4[tid] = a0;
    out4[tid + 256] = a1;
}

extern "C" void kernel_launch(void* const* d_in, const int* in_sizes, int n_in,
                              void* d_out, int out_size, void* d_ws, size_t ws_size,
                              hipStream_t stream) {
    const float* query = (const float*)d_in[0];
    const float* qset  = (const float*)d_in[1];
    const float* tset  = (const float*)d_in[2];
    float* out = (float*)d_out;

    char* ws = (char*)d_ws;
    size_t off = 0;
    unsigned char* A8 = (unsigned char*)(ws + off); off += (size_t)B_DIM * D_DIM;   // 4 MB
    unsigned char* B8 = (unsigned char*)(ws + off); off += (size_t)M_DIM * D_DIM;   // 16 MB
    float* rq   = (float*)(ws + off);  off += B_DIM * sizeof(float);
    float* rs   = (float*)(ws + off);  off += M_DIM * sizeof(float);
    int* ccnt   = (int*)(ws + off);    off += B_DIM * sizeof(int);
    int* cidx   = (int*)(ws + off);    off += (size_t)B_DIM * CAP * sizeof(int);    // 16 MB

    hipLaunchKernelGGL(prep_kernel, dim3(B_DIM + M_DIM), dim3(256), 0, stream,
                       query, qset, A8, B8, rq, rs, ccnt);
    hipLaunchKernelGGL(gemm_screen, dim3(M_DIM / 128, B_DIM / 128), dim3(256), 0, stream,
                       A8, B8, ccnt, cidx);
    hipLaunchKernelGGL(stats_gather, dim3(B_DIM), dim3(256), 0, stream,
                       query, qset, tset, rq, rs, ccnt, cidx, out);
}